// Round 1
// baseline (287.584 us; speedup 1.0000x reference)
//
#include <hip/hip_runtime.h>
#include <math.h>

typedef float f32x4 __attribute__((ext_vector_type(4)));
typedef float f32x2 __attribute__((ext_vector_type(2)));
typedef int   i32x4 __attribute__((ext_vector_type(4)));
typedef unsigned short u16;
typedef u16 u16x4 __attribute__((ext_vector_type(4)));

#define BDIM 32
#define SDIM 128
#define NCAPS 16
#define DCAPS 512
#define MG 4096   // BDIM*SDIM
#define NG 8192   // NCAPS*DCAPS
#define KG 1024

__device__ __forceinline__ u16 f2bf(float f) {
  unsigned u = __builtin_bit_cast(unsigned, f);
  u += 0x7fffu + ((u >> 16) & 1u);   // RNE
  return (u16)(u >> 16);
}
__device__ __forceinline__ float bflo(unsigned u) {
  return __builtin_bit_cast(float, u << 16);
}
__device__ __forceinline__ float bfhi(unsigned u) {
  return __builtin_bit_cast(float, u & 0xffff0000u);
}

__device__ __forceinline__ void gload16(const void* g, void* l) {
  __builtin_amdgcn_global_load_lds(
      (const __attribute__((address_space(1))) void*)g,
      (__attribute__((address_space(3))) void*)l, 16, 0, 0);
}

__device__ __forceinline__ f32x4 mfma_bf16(i32x4 a, i32x4 b, f32x4 c) {
  asm("v_mfma_f32_16x16x32_bf16 %0, %1, %2, %0" : "+v"(c) : "v"(a), "v"(b));
  return c;
}

// ---- x f32 (4096x1024) -> bf16 same layout ----
__global__ __launch_bounds__(256) void k_convx(const float* __restrict__ x,
                                               u16* __restrict__ xb) {
  int i = blockIdx.x * 256 + threadIdx.x;   // 4096 blocks * 256 = 1048576 = MG*KG/4
  f32x4 v = ((const f32x4*)x)[i];
  u16x4 r = { f2bf(v.x), f2bf(v.y), f2bf(v.z), f2bf(v.w) };
  ((u16x4*)xb)[i] = r;
}

// ---- W f32 (1024x8192) -> Wt bf16 (8192x1024) ----
__global__ __launch_bounds__(256) void k_transW(const float* __restrict__ W,
                                                u16* __restrict__ wt) {
  __shared__ float tile[32][33];
  const int n0 = blockIdx.x * 32;   // 256 blocks
  const int k0 = blockIdx.y * 32;   // 32 blocks
  const int tx = threadIdx.x & 31;
  const int ty = threadIdx.x >> 5;  // 0..7
#pragma unroll
  for (int r = 0; r < 32; r += 8)
    tile[ty + r][tx] = W[(size_t)(k0 + ty + r) * NG + n0 + tx];
  __syncthreads();
#pragma unroll
  for (int r = 0; r < 32; r += 8)
    wt[(size_t)(n0 + ty + r) * KG + k0 + tx] = f2bf(tile[tx][ty + r]);
}

// ---- init C1 = 1/16, B = 0 ----
__global__ __launch_bounds__(256) void k_init(float* __restrict__ C0,
                                              float* __restrict__ Bws) {
  int i = blockIdx.x * 256 + threadIdx.x;   // 64 blocks * 256 = 16384 f32x4
  f32x4 c = { 0.0625f, 0.0625f, 0.0625f, 0.0625f };
  f32x4 z = {};
  ((f32x4*)C0)[i] = c;
  ((f32x4*)Bws)[i] = z;
}

// ---- GEMM + tanh: uhat[m][ncol] = tanh(sum_k xb[m][k]*wt[ncol][k]), bf16 out ----
__global__ __launch_bounds__(256) void k_gemm_tanh(const u16* __restrict__ xb,
                                                   const u16* __restrict__ wt,
                                                   u16* __restrict__ uhat) {
  __shared__ u16 As[128 * 32];
  __shared__ u16 Bs[128 * 32];
  const int m0 = blockIdx.y * 128;
  const int n0 = blockIdx.x * 128;
  const int t = threadIdx.x;
  const int lane = t & 63;
  const int wave = t >> 6;
  const int wr = (wave >> 1) * 64;
  const int wc = (wave & 1) * 64;
  f32x4 acc[4][4] = {};

  const int r0 = t >> 2;              // shot0 rows 0..63
  const int r1 = (256 + t) >> 2;      // shot1 rows 64..127
  const int c0 = (t & 3) * 8;
  const u16* ga0 = xb + (size_t)(m0 + r0) * KG + c0;
  const u16* ga1 = xb + (size_t)(m0 + r1) * KG + c0;
  const u16* gb0 = wt + (size_t)(n0 + r0) * KG + c0;
  const u16* gb1 = wt + (size_t)(n0 + r1) * KG + c0;
  u16* la0 = &As[t * 8];
  u16* la1 = &As[(256 + t) * 8];
  u16* lb0 = &Bs[t * 8];
  u16* lb1 = &Bs[(256 + t) * 8];

  const int am = lane & 15;
  const int ak = (lane >> 4) * 8;

  for (int kt = 0; kt < KG; kt += 32) {
    gload16(ga0 + kt, la0);
    gload16(ga1 + kt, la1);
    gload16(gb0 + kt, lb0);
    gload16(gb1 + kt, lb1);
    __syncthreads();
    i32x4 af[4], bf[4];
#pragma unroll
    for (int mi = 0; mi < 4; ++mi)
      af[mi] = *(const i32x4*)&As[(wr + mi * 16 + am) * 32 + ak];
#pragma unroll
    for (int ni = 0; ni < 4; ++ni)
      bf[ni] = *(const i32x4*)&Bs[(wc + ni * 16 + am) * 32 + ak];
#pragma unroll
    for (int mi = 0; mi < 4; ++mi)
#pragma unroll
      for (int ni = 0; ni < 4; ++ni)
        acc[mi][ni] = mfma_bf16(af[mi], bf[ni], acc[mi][ni]);
    __syncthreads();
  }

  const int crow0 = (lane >> 4) * 4;
  const int ccol = lane & 15;
#pragma unroll
  for (int mi = 0; mi < 4; ++mi)
#pragma unroll
    for (int ni = 0; ni < 4; ++ni)
#pragma unroll
      for (int j = 0; j < 4; ++j) {
        int row = m0 + wr + mi * 16 + crow0 + j;
        int col = n0 + wc + ni * 16 + ccol;
        uhat[(size_t)row * NG + col] = f2bf(tanhf(acc[mi][ni][j]));
      }
}

// ---- S-pass + squash: block (n,b); V[b,n,d] = squash(sum_s C[b,s,n]*uhat[b,s,n,d]) ----
__global__ __launch_bounds__(256) void k_spass(const u16* __restrict__ uhat,
                                               const float* __restrict__ C,
                                               float* __restrict__ V) {
  const int n = blockIdx.x;   // 16
  const int b = blockIdx.y;   // 32
  const int t = threadIdx.x;
  __shared__ float cl[128];
  __shared__ float red[4];
  if (t < 128) cl[t] = C[((size_t)b * 128 + t) * 16 + n];
  __syncthreads();
  const u16* up = uhat + (((size_t)b * 128) * 16 + n) * 512 + 2 * t;
  float a0 = 0.f, a1 = 0.f;
#pragma unroll 4
  for (int s = 0; s < 128; ++s) {
    unsigned u = *(const unsigned*)(up + (size_t)s * 8192);
    float c = cl[s];
    a0 = fmaf(c, bflo(u), a0);
    a1 = fmaf(c, bfhi(u), a1);
  }
  float ss = a0 * a0 + a1 * a1;
#pragma unroll
  for (int m = 1; m < 64; m <<= 1) ss += __shfl_xor(ss, m);
  if ((t & 63) == 0) red[t >> 6] = ss;
  __syncthreads();
  float tot = red[0] + red[1] + red[2] + red[3];
  float r = 1.0f / sqrtf(tot + 1e-7f);
  f32x2 vv = { a0 * r, a1 * r };
  *(f32x2*)(V + ((size_t)b * 16 + n) * 512 + 2 * t) = vv;
}

// ---- B-update + fused next softmax: block (b,s) ----
__global__ __launch_bounds__(256) void k_bupdate(const u16* __restrict__ uhat,
                                                 const float* __restrict__ V,
                                                 float* __restrict__ Bws,
                                                 float* __restrict__ Cnext,
                                                 float* __restrict__ Blog) {
  const int bs = blockIdx.x;   // 4096
  const int b = bs >> 7;
  const int t = threadIdx.x;
  const int n = t >> 4;
  const int j = t & 15;
  const u16* up = uhat + ((size_t)bs * 16 + n) * 512 + j * 32;
  const float* vp = V + ((size_t)b * 16 + n) * 512 + j * 32;
  float dot = 0.f;
#pragma unroll
  for (int q = 0; q < 4; ++q) {
    i32x4 u = *(const i32x4*)(up + q * 8);
    f32x4 v0 = *(const f32x4*)(vp + q * 8);
    f32x4 v1 = *(const f32x4*)(vp + q * 8 + 4);
    dot = fmaf(bflo(u.x), v0.x, dot);
    dot = fmaf(bfhi(u.x), v0.y, dot);
    dot = fmaf(bflo(u.y), v0.z, dot);
    dot = fmaf(bfhi(u.y), v0.w, dot);
    dot = fmaf(bflo(u.z), v1.x, dot);
    dot = fmaf(bfhi(u.z), v1.y, dot);
    dot = fmaf(bflo(u.w), v1.z, dot);
    dot = fmaf(bfhi(u.w), v1.w, dot);
  }
#pragma unroll
  for (int m = 1; m < 16; m <<= 1) dot += __shfl_xor(dot, m);
  __shared__ float bl[16];
  if (j == 0) bl[n] = Bws[(size_t)bs * 16 + n] + dot;
  __syncthreads();
  if (t < 16) {
    float mx = -1e30f;
#pragma unroll
    for (int k2 = 0; k2 < 16; ++k2) mx = fmaxf(mx, bl[k2]);
    float e = expf(bl[t] - mx);
    float sum = 0.f;
#pragma unroll
    for (int k2 = 0; k2 < 16; ++k2) sum += expf(bl[k2] - mx);
    size_t o = (size_t)bs * 16 + t;
    Cnext[o] = e / sum;
    float bn = bl[t];
    Bws[o] = bn;
    if (Blog) Blog[o] = bn;
  }
}

extern "C" void kernel_launch(void* const* d_in, const int* in_sizes, int n_in,
                              void* d_out, int out_size, void* d_ws, size_t ws_size,
                              hipStream_t stream) {
  const float* x = (const float*)d_in[0];
  const float* W = (const float*)d_in[1];
  float* out = (float*)d_out;
  float* Vout = out;                          // 32*16*512 = 262144
  float* Cout = out + 262144;                 // 3*32*128*16 = 196608
  float* Blog = out + 262144 + 196608;        // 32*128*16 = 65536

  char* ws = (char*)d_ws;
  u16* uhat = (u16*)ws;                                   // 67108864 B
  u16* xb   = (u16*)(ws + 67108864);                      // 8388608 B
  u16* wt   = (u16*)(ws + 67108864 + 8388608);            // 16777216 B
  float* Vws = (float*)(ws + 92274688);                   // 1048576 B
  float* Bws = (float*)(ws + 93323264);                   // 262144 B

  k_convx<<<4096, 256, 0, stream>>>(x, xb);
  k_transW<<<dim3(256, 32), 256, 0, stream>>>(W, wt);
  k_init<<<64, 256, 0, stream>>>(Cout, Bws);
  k_gemm_tanh<<<dim3(64, 32), 256, 0, stream>>>(xb, wt, uhat);
  // iter 1: C1 uniform (already written), S1 -> V1, B1 = uhat.V1, C2
  k_spass<<<dim3(16, 32), 256, 0, stream>>>(uhat, Cout, Vws);
  k_bupdate<<<4096, 256, 0, stream>>>(uhat, Vws, Bws, Cout + 65536, nullptr);
  // iter 2: S2 -> V2, B2 = B1 + uhat.V2 (= B_logits), C3
  k_spass<<<dim3(16, 32), 256, 0, stream>>>(uhat, Cout + 65536, Vws);
  k_bupdate<<<4096, 256, 0, stream>>>(uhat, Vws, Bws, Cout + 2 * 65536, Blog);
  // iter 3: S3 -> V3 = output V (no B-update needed)
  k_spass<<<dim3(16, 32), 256, 0, stream>>>(uhat, Cout + 2 * 65536, Vout);
}

// Round 4
// 272.854 us; speedup vs baseline: 1.0540x; 1.0540x over previous
//
#include <hip/hip_runtime.h>
#include <math.h>

typedef float f32x4 __attribute__((ext_vector_type(4)));
typedef float f32x2 __attribute__((ext_vector_type(2)));
typedef int   i32x4 __attribute__((ext_vector_type(4)));
typedef unsigned short u16;
typedef u16 u16x4 __attribute__((ext_vector_type(4)));

#define NG 8192   // NCAPS*DCAPS
#define KG 1024

__device__ __forceinline__ u16 f2bf(float f) {
  unsigned u = __builtin_bit_cast(unsigned, f);
  u += 0x7fffu + ((u >> 16) & 1u);   // RNE
  return (u16)(u >> 16);
}
__device__ __forceinline__ float bflo(unsigned u) {
  return __builtin_bit_cast(float, u << 16);
}
__device__ __forceinline__ float bfhi(unsigned u) {
  return __builtin_bit_cast(float, u & 0xffff0000u);
}

__device__ __forceinline__ void gload16(const void* g, void* l) {
  __builtin_amdgcn_global_load_lds(
      (const __attribute__((address_space(1))) void*)g,
      (__attribute__((address_space(3))) void*)l, 16, 0, 0);
}

__device__ __forceinline__ f32x4 mfma_bf16(i32x4 a, i32x4 b, f32x4 c) {
  asm("v_mfma_f32_16x16x32_bf16 %0, %1, %2, %0" : "+v"(c) : "v"(a), "v"(b));
  return c;
}

__device__ __forceinline__ float fast_tanh(float x) {
  float ax = fabsf(x);
  float e = __expf(-2.0f * ax);
  float r = (1.0f - e) * __frcp_rn(1.0f + e);
  return copysignf(r, x);
}

// ---- x f32 (4096x1024) -> bf16 same layout ---- (round-1 proven)
__global__ __launch_bounds__(256) void k_convx(const float* __restrict__ x,
                                               u16* __restrict__ xb) {
  int i = blockIdx.x * 256 + threadIdx.x;
  f32x4 v = ((const f32x4*)x)[i];
  u16x4 r = { f2bf(v.x), f2bf(v.y), f2bf(v.z), f2bf(v.w) };
  ((u16x4*)xb)[i] = r;
}

// ---- W f32 (1024x8192) -> Wt bf16 (8192x1024) ---- (round-1 proven)
__global__ __launch_bounds__(256) void k_transW(const float* __restrict__ W,
                                                u16* __restrict__ wt) {
  __shared__ float tile[32][33];
  const int n0 = blockIdx.x * 32;
  const int k0 = blockIdx.y * 32;
  const int tx = threadIdx.x & 31;
  const int ty = threadIdx.x >> 5;
#pragma unroll
  for (int r = 0; r < 32; r += 8)
    tile[ty + r][tx] = W[(size_t)(k0 + ty + r) * NG + n0 + tx];
  __syncthreads();
#pragma unroll
  for (int r = 0; r < 32; r += 8)
    wt[(size_t)(n0 + ty + r) * KG + k0 + tx] = f2bf(tile[tx][ty + r]);
}

// ---- init C1 = 1/16 and B = 0 ---- (round-1 proven)
__global__ __launch_bounds__(256) void k_init(float* __restrict__ C0,
                                              float* __restrict__ Bws) {
  int i = blockIdx.x * 256 + threadIdx.x;   // 64 blocks * 256 = 16384 f32x4
  f32x4 c = { 0.0625f, 0.0625f, 0.0625f, 0.0625f };
  f32x4 z = {};
  ((f32x4*)C0)[i] = c;
  ((f32x4*)Bws)[i] = z;
}

// ---- GEMM + tanh: uhat = tanh(xb @ wt^T), bf16 out ----
// Round-1 structure with BK=64 via two independent round-1-style half-buffers.
__global__ __launch_bounds__(256) void k_gemm_tanh(const u16* __restrict__ xb,
                                                   const u16* __restrict__ wt,
                                                   u16* __restrict__ uhat) {
  __shared__ u16 As[2][128 * 32];   // [kh][row*32 + c]
  __shared__ u16 Bs[2][128 * 32];
  const int m0 = blockIdx.y * 128;
  const int n0 = blockIdx.x * 128;
  const int t = threadIdx.x;
  const int lane = t & 63;
  const int wave = t >> 6;
  const int wr = (wave >> 1) * 64;
  const int wc = (wave & 1) * 64;
  f32x4 acc[4][4] = {};

  const int r0 = t >> 2;              // rows 0..63
  const int r1 = 64 + (t >> 2);       // rows 64..127
  const int c0 = (t & 3) * 8;
  const u16* ga0 = xb + (size_t)(m0 + r0) * KG + c0;
  const u16* ga1 = xb + (size_t)(m0 + r1) * KG + c0;
  const u16* gb0 = wt + (size_t)(n0 + r0) * KG + c0;
  const u16* gb1 = wt + (size_t)(n0 + r1) * KG + c0;

  const int am = lane & 15;
  const int ak = (lane >> 4) * 8;

  for (int kt = 0; kt < KG; kt += 64) {
#pragma unroll
    for (int kh = 0; kh < 2; ++kh) {
      const int ko = kt + kh * 32;
      gload16(ga0 + ko, &As[kh][t * 8]);
      gload16(ga1 + ko, &As[kh][(256 + t) * 8]);
      gload16(gb0 + ko, &Bs[kh][t * 8]);
      gload16(gb1 + ko, &Bs[kh][(256 + t) * 8]);
    }
    __syncthreads();
#pragma unroll
    for (int kh = 0; kh < 2; ++kh) {
      i32x4 af[4], bf[4];
#pragma unroll
      for (int mi = 0; mi < 4; ++mi)
        af[mi] = *(const i32x4*)&As[kh][(wr + mi * 16 + am) * 32 + ak];
#pragma unroll
      for (int ni = 0; ni < 4; ++ni)
        bf[ni] = *(const i32x4*)&Bs[kh][(wc + ni * 16 + am) * 32 + ak];
#pragma unroll
      for (int mi = 0; mi < 4; ++mi)
#pragma unroll
        for (int ni = 0; ni < 4; ++ni)
          acc[mi][ni] = mfma_bf16(af[mi], bf[ni], acc[mi][ni]);
    }
    __syncthreads();
  }

  const int crow0 = (lane >> 4) * 4;
  const int ccol = lane & 15;
#pragma unroll
  for (int mi = 0; mi < 4; ++mi)
#pragma unroll
    for (int ni = 0; ni < 4; ++ni)
#pragma unroll
      for (int j = 0; j < 4; ++j) {
        int row = m0 + wr + mi * 16 + crow0 + j;
        int col = n0 + wc + ni * 16 + ccol;
        uhat[(size_t)row * NG + col] = f2bf(fast_tanh(acc[mi][ni][j]));
      }
}

// ---- S-pass + squash: block (n,b); V[b,n,d] = squash(sum_s C[b,s,n]*uhat[b,s,n,d])
// Vectorized: 16B loads, 4 s-streams (one per wave), LDS 4-way d-reduce.
__global__ __launch_bounds__(256) void k_spass(const u16* __restrict__ uhat,
                                               const float* __restrict__ C,
                                               float* __restrict__ V) {
  const int n = blockIdx.x;   // 16
  const int b = blockIdx.y;   // 32
  const int t = threadIdx.x;
  const int g = t >> 6;       // wave = s-stream (s ≡ g mod 4)
  const int dl = t & 63;      // d-block: elems dl*8 .. dl*8+8
  __shared__ float cl[128];
  __shared__ float Sred[4][512];   // 8KB
  if (t < 128) cl[t] = C[((size_t)b * 128 + t) * 16 + n];
  __syncthreads();

  const u16* up = uhat + (((size_t)b * 128) * 16 + n) * 512 + dl * 8;
  float a[8] = {};
#pragma unroll 4
  for (int i = 0; i < 32; ++i) {
    const int s = g + i * 4;
    i32x4 u = *(const i32x4*)(up + (size_t)s * NG);
    float c = cl[s];
    a[0] = fmaf(c, bflo(u.x), a[0]); a[1] = fmaf(c, bfhi(u.x), a[1]);
    a[2] = fmaf(c, bflo(u.y), a[2]); a[3] = fmaf(c, bfhi(u.y), a[3]);
    a[4] = fmaf(c, bflo(u.z), a[4]); a[5] = fmaf(c, bfhi(u.z), a[5]);
    a[6] = fmaf(c, bflo(u.w), a[6]); a[7] = fmaf(c, bfhi(u.w), a[7]);
  }
#pragma unroll
  for (int e = 0; e < 8; ++e) Sred[g][dl * 8 + e] = a[e];
  __syncthreads();

  if (g == 0) {   // wave 0 finalizes (no barrier below — safe divergence)
    float S[8];
    float ss = 0.f;
#pragma unroll
    for (int e = 0; e < 8; ++e) {
      int d = dl * 8 + e;
      S[e] = Sred[0][d] + Sred[1][d] + Sred[2][d] + Sred[3][d];
      ss = fmaf(S[e], S[e], ss);
    }
#pragma unroll
    for (int m = 1; m < 64; m <<= 1) ss += __shfl_xor(ss, m);
    float r = rsqrtf(ss + 1e-7f);
    float* vp = V + ((size_t)b * 16 + n) * 512 + dl * 8;
    f32x4 v0 = { S[0] * r, S[1] * r, S[2] * r, S[3] * r };
    f32x4 v1 = { S[4] * r, S[5] * r, S[6] * r, S[7] * r };
    *(f32x4*)vp = v0;
    *(f32x4*)(vp + 4) = v1;
  }
}

// ---- B-update + fused next softmax: block (b,s) ---- (round-1 proven)
__global__ __launch_bounds__(256) void k_bupdate(const u16* __restrict__ uhat,
                                                 const float* __restrict__ V,
                                                 float* __restrict__ Bws,
                                                 float* __restrict__ Cnext,
                                                 float* __restrict__ Blog) {
  const int bs = blockIdx.x;   // 4096
  const int b = bs >> 7;
  const int t = threadIdx.x;
  const int n = t >> 4;
  const int j = t & 15;
  const u16* up = uhat + ((size_t)bs * 16 + n) * 512 + j * 32;
  const float* vp = V + ((size_t)b * 16 + n) * 512 + j * 32;
  float dot = 0.f;
#pragma unroll
  for (int q = 0; q < 4; ++q) {
    i32x4 u = *(const i32x4*)(up + q * 8);
    f32x4 v0 = *(const f32x4*)(vp + q * 8);
    f32x4 v1 = *(const f32x4*)(vp + q * 8 + 4);
    dot = fmaf(bflo(u.x), v0.x, dot);
    dot = fmaf(bfhi(u.x), v0.y, dot);
    dot = fmaf(bflo(u.y), v0.z, dot);
    dot = fmaf(bfhi(u.y), v0.w, dot);
    dot = fmaf(bflo(u.z), v1.x, dot);
    dot = fmaf(bfhi(u.z), v1.y, dot);
    dot = fmaf(bflo(u.w), v1.z, dot);
    dot = fmaf(bfhi(u.w), v1.w, dot);
  }
#pragma unroll
  for (int m = 1; m < 16; m <<= 1) dot += __shfl_xor(dot, m);
  __shared__ float bl[16];
  if (j == 0) bl[n] = Bws[(size_t)bs * 16 + n] + dot;
  __syncthreads();
  if (t < 16) {
    float mx = -1e30f;
#pragma unroll
    for (int k2 = 0; k2 < 16; ++k2) mx = fmaxf(mx, bl[k2]);
    float e = expf(bl[t] - mx);
    float sum = 0.f;
#pragma unroll
    for (int k2 = 0; k2 < 16; ++k2) sum += expf(bl[k2] - mx);
    size_t o = (size_t)bs * 16 + t;
    Cnext[o] = e / sum;
    float bn = bl[t];
    Bws[o] = bn;
    if (Blog) Blog[o] = bn;
  }
}

extern "C" void kernel_launch(void* const* d_in, const int* in_sizes, int n_in,
                              void* d_out, int out_size, void* d_ws, size_t ws_size,
                              hipStream_t stream) {
  const float* x = (const float*)d_in[0];
  const float* W = (const float*)d_in[1];
  float* out = (float*)d_out;
  float* Vout = out;                          // 32*16*512 = 262144
  float* Cout = out + 262144;                 // 3*32*128*16 = 196608
  float* Blog = out + 262144 + 196608;        // 32*128*16 = 65536

  char* ws = (char*)d_ws;
  u16* uhat = (u16*)ws;                                   // 67108864 B
  u16* xb   = (u16*)(ws + 67108864);                      // 8388608 B
  u16* wt   = (u16*)(ws + 67108864 + 8388608);            // 16777216 B
  float* Vws = (float*)(ws + 92274688);                   // 1048576 B
  float* Bws = (float*)(ws + 93323264);                   // 262144 B  (peak 89.25MB, round-1 proven)

  k_convx<<<4096, 256, 0, stream>>>(x, xb);
  k_transW<<<dim3(256, 32), 256, 0, stream>>>(W, wt);
  k_init<<<64, 256, 0, stream>>>(Cout, Bws);
  k_gemm_tanh<<<dim3(64, 32), 256, 0, stream>>>(xb, wt, uhat);
  // iter 1: C1 uniform (already written), S1 -> V1, B1 = uhat.V1, C2
  k_spass<<<dim3(16, 32), 256, 0, stream>>>(uhat, Cout, Vws);
  k_bupdate<<<4096, 256, 0, stream>>>(uhat, Vws, Bws, Cout + 65536, nullptr);
  // iter 2: S2 -> V2, B2 = B1 + uhat.V2 (= B_logits), C3
  k_spass<<<dim3(16, 32), 256, 0, stream>>>(uhat, Cout + 65536, Vws);
  k_bupdate<<<4096, 256, 0, stream>>>(uhat, Vws, Bws, Cout + 2 * 65536, Blog);
  // iter 3: S3 -> V3 = output V (no B-update needed)
  k_spass<<<dim3(16, 32), 256, 0, stream>>>(uhat, Cout + 2 * 65536, Vout);
}

// Round 5
// 237.293 us; speedup vs baseline: 1.2119x; 1.1499x over previous
//
#include <hip/hip_runtime.h>
#include <math.h>

typedef float f32x4 __attribute__((ext_vector_type(4)));
typedef int   i32x4 __attribute__((ext_vector_type(4)));
typedef unsigned short u16;
typedef u16 u16x4 __attribute__((ext_vector_type(4)));

#define NG 8192   // NCAPS*DCAPS
#define KG 1024

__device__ __forceinline__ u16 f2bf(float f) {
  unsigned u = __builtin_bit_cast(unsigned, f);
  u += 0x7fffu + ((u >> 16) & 1u);   // RNE
  return (u16)(u >> 16);
}
__device__ __forceinline__ float bflo(unsigned u) {
  return __builtin_bit_cast(float, u << 16);
}
__device__ __forceinline__ float bfhi(unsigned u) {
  return __builtin_bit_cast(float, u & 0xffff0000u);
}

__device__ __forceinline__ void gload16(const void* g, void* l) {
  __builtin_amdgcn_global_load_lds(
      (const __attribute__((address_space(1))) void*)g,
      (__attribute__((address_space(3))) void*)l, 16, 0, 0);
}

__device__ __forceinline__ f32x4 mfma_bf16(i32x4 a, i32x4 b, f32x4 c) {
  asm("v_mfma_f32_16x16x32_bf16 %0, %1, %2, %0" : "+v"(c) : "v"(a), "v"(b));
  return c;
}

__device__ __forceinline__ float fast_tanh(float x) {
  float ax = fabsf(x);
  float e = __expf(-2.0f * ax);
  float r = (1.0f - e) * __frcp_rn(1.0f + e);
  return copysignf(r, x);
}

// ---- x f32 (4096x1024) -> bf16 same layout ---- (round-1 proven)
__global__ __launch_bounds__(256) void k_convx(const float* __restrict__ x,
                                               u16* __restrict__ xb) {
  int i = blockIdx.x * 256 + threadIdx.x;
  f32x4 v = ((const f32x4*)x)[i];
  u16x4 r = { f2bf(v.x), f2bf(v.y), f2bf(v.z), f2bf(v.w) };
  ((u16x4*)xb)[i] = r;
}

// ---- W f32 (1024x8192) -> Wt bf16 (8192x1024) ---- (round-1 proven)
__global__ __launch_bounds__(256) void k_transW(const float* __restrict__ W,
                                                u16* __restrict__ wt) {
  __shared__ float tile[32][33];
  const int n0 = blockIdx.x * 32;
  const int k0 = blockIdx.y * 32;
  const int tx = threadIdx.x & 31;
  const int ty = threadIdx.x >> 5;
#pragma unroll
  for (int r = 0; r < 32; r += 8)
    tile[ty + r][tx] = W[(size_t)(k0 + ty + r) * NG + n0 + tx];
  __syncthreads();
#pragma unroll
  for (int r = 0; r < 32; r += 8)
    wt[(size_t)(n0 + ty + r) * KG + k0 + tx] = f2bf(tile[tx][ty + r]);
}

// ---- init C1 = 1/16 and B = 0 ---- (round-4 proven)
__global__ __launch_bounds__(256) void k_init(float* __restrict__ C0,
                                              float* __restrict__ Bws) {
  int i = blockIdx.x * 256 + threadIdx.x;   // 64 blocks * 256 = 16384 f32x4
  f32x4 c = { 0.0625f, 0.0625f, 0.0625f, 0.0625f };
  f32x4 z = {};
  ((f32x4*)C0)[i] = c;
  ((f32x4*)Bws)[i] = z;
}

// ---- GEMM + tanh: uhat = tanh(xb @ wt^T), bf16 out ---- (round-4 proven)
__global__ __launch_bounds__(256) void k_gemm_tanh(const u16* __restrict__ xb,
                                                   const u16* __restrict__ wt,
                                                   u16* __restrict__ uhat) {
  __shared__ u16 As[2][128 * 32];
  __shared__ u16 Bs[2][128 * 32];
  const int m0 = blockIdx.y * 128;
  const int n0 = blockIdx.x * 128;
  const int t = threadIdx.x;
  const int lane = t & 63;
  const int wave = t >> 6;
  const int wr = (wave >> 1) * 64;
  const int wc = (wave & 1) * 64;
  f32x4 acc[4][4] = {};

  const int r0 = t >> 2;
  const int r1 = 64 + (t >> 2);
  const int c0 = (t & 3) * 8;
  const u16* ga0 = xb + (size_t)(m0 + r0) * KG + c0;
  const u16* ga1 = xb + (size_t)(m0 + r1) * KG + c0;
  const u16* gb0 = wt + (size_t)(n0 + r0) * KG + c0;
  const u16* gb1 = wt + (size_t)(n0 + r1) * KG + c0;

  const int am = lane & 15;
  const int ak = (lane >> 4) * 8;

  for (int kt = 0; kt < KG; kt += 64) {
#pragma unroll
    for (int kh = 0; kh < 2; ++kh) {
      const int ko = kt + kh * 32;
      gload16(ga0 + ko, &As[kh][t * 8]);
      gload16(ga1 + ko, &As[kh][(256 + t) * 8]);
      gload16(gb0 + ko, &Bs[kh][t * 8]);
      gload16(gb1 + ko, &Bs[kh][(256 + t) * 8]);
    }
    __syncthreads();
#pragma unroll
    for (int kh = 0; kh < 2; ++kh) {
      i32x4 af[4], bf[4];
#pragma unroll
      for (int mi = 0; mi < 4; ++mi)
        af[mi] = *(const i32x4*)&As[kh][(wr + mi * 16 + am) * 32 + ak];
#pragma unroll
      for (int ni = 0; ni < 4; ++ni)
        bf[ni] = *(const i32x4*)&Bs[kh][(wc + ni * 16 + am) * 32 + ak];
#pragma unroll
      for (int mi = 0; mi < 4; ++mi)
#pragma unroll
        for (int ni = 0; ni < 4; ++ni)
          acc[mi][ni] = mfma_bf16(af[mi], bf[ni], acc[mi][ni]);
    }
    __syncthreads();
  }

  const int crow0 = (lane >> 4) * 4;
  const int ccol = lane & 15;
#pragma unroll
  for (int mi = 0; mi < 4; ++mi)
#pragma unroll
    for (int ni = 0; ni < 4; ++ni)
#pragma unroll
      for (int j = 0; j < 4; ++j) {
        int row = m0 + wr + mi * 16 + crow0 + j;
        int col = n0 + wc + ni * 16 + ccol;
        uhat[(size_t)row * NG + col] = f2bf(fast_tanh(acc[mi][ni][j]));
      }
}

// ---- Fused routing step for one (b,n): stage U in LDS once, then
//      S = sum_s C[s]*U[s,:]; V = S/sqrt(||S||^2+eps);
//      MODE 0: dot[s] = U[s,:].V -> dst (dotB);  MODE 1: V -> dst (Vout).
// LDS chunk-swizzle: LDS chunk j of row r holds global chunk j^(r&7)
// (pre-swizzled per-lane GLOBAL src; LDS dest stays linear for gload_lds).
template <int MODE>
__global__ __launch_bounds__(256) void k_fused(const u16* __restrict__ uhat,
                                               const float* __restrict__ C,
                                               float* __restrict__ dst) {
  __shared__ u16 Us[128 * 512];    // 128 KB
  __shared__ float cl[128];
  __shared__ float Sred[4][512];   // 8 KB; Sred[0] reused as V after reduce
  const int n = blockIdx.x;   // 16
  const int b = blockIdx.y;   // 32
  const int t = threadIdx.x;
  const int lane = t & 63;
  const int wave = t >> 6;
  const u16* Ub = uhat + ((size_t)b * 128) * NG + n * 512;

  if (t < 128) cl[t] = C[((size_t)b * 128 + t) * 16 + n];

  // stage: each wave stages one full 1KB row per shot, 32 shots
#pragma unroll 8
  for (int i = 0; i < 32; ++i) {
    const int row = i * 4 + wave;
    gload16(Ub + (size_t)row * NG + ((lane ^ (row & 7)) * 8),
            &Us[row * 512 + lane * 8]);
  }
  __syncthreads();   // drains vmcnt + lgkmcnt

  // S-phase: wave g owns s = g mod 4; lane owns global chunk dl (8 d-elems)
  float a[8] = {};
#pragma unroll 8
  for (int i = 0; i < 32; ++i) {
    const int s = wave + i * 4;
    i32x4 u = *(const i32x4*)&Us[s * 512 + ((lane ^ (s & 7)) * 8)];
    float c = cl[s];
    a[0] = fmaf(c, bflo(u.x), a[0]); a[1] = fmaf(c, bfhi(u.x), a[1]);
    a[2] = fmaf(c, bflo(u.y), a[2]); a[3] = fmaf(c, bfhi(u.y), a[3]);
    a[4] = fmaf(c, bflo(u.z), a[4]); a[5] = fmaf(c, bfhi(u.z), a[5]);
    a[6] = fmaf(c, bflo(u.w), a[6]); a[7] = fmaf(c, bfhi(u.w), a[7]);
  }
#pragma unroll
  for (int e = 0; e < 8; ++e) Sred[wave][lane * 8 + e] = a[e];
  __syncthreads();

  if (wave == 0) {
    float S[8];
    float ss = 0.f;
#pragma unroll
    for (int e = 0; e < 8; ++e) {
      int d = lane * 8 + e;
      S[e] = Sred[0][d] + Sred[1][d] + Sred[2][d] + Sred[3][d];
      ss = fmaf(S[e], S[e], ss);
    }
#pragma unroll
    for (int m = 1; m < 64; m <<= 1) ss += __shfl_xor(ss, m);
    float r = rsqrtf(ss + 1e-7f);
    if (MODE == 1) {
      float* vp = dst + ((size_t)b * 16 + n) * 512 + lane * 8;
      f32x4 v0 = { S[0] * r, S[1] * r, S[2] * r, S[3] * r };
      f32x4 v1 = { S[4] * r, S[5] * r, S[6] * r, S[7] * r };
      *(f32x4*)vp = v0;
      *(f32x4*)(vp + 4) = v1;
    } else {
#pragma unroll
      for (int e = 0; e < 8; ++e) Sred[0][lane * 8 + e] = S[e] * r;  // V
    }
  }

  if (MODE == 0) {
    __syncthreads();
    const int s = t >> 1, h = t & 1;   // s: 32 per wave; h: d-half
    const float* Vl = &Sred[0][0];
    float dot = 0.f;
#pragma unroll 8
    for (int i = 0; i < 32; ++i) {
      const int chunk = h * 32 + i;    // global chunk
      i32x4 u = *(const i32x4*)&Us[s * 512 + ((chunk ^ (s & 7)) * 8)];
      const float* vp = Vl + chunk * 8;   // broadcast across same-h lanes
      f32x4 v0 = *(const f32x4*)vp;
      f32x4 v1 = *(const f32x4*)(vp + 4);
      dot = fmaf(bflo(u.x), v0.x, dot);
      dot = fmaf(bfhi(u.x), v0.y, dot);
      dot = fmaf(bflo(u.y), v0.z, dot);
      dot = fmaf(bfhi(u.y), v0.w, dot);
      dot = fmaf(bflo(u.z), v1.x, dot);
      dot = fmaf(bfhi(u.z), v1.y, dot);
      dot = fmaf(bflo(u.w), v1.z, dot);
      dot = fmaf(bfhi(u.w), v1.w, dot);
    }
    dot += __shfl_xor(dot, 1);
    if (h == 0) dst[((size_t)b * 128 + s) * 16 + n] = dot;
  }
}

// ---- B += dot; Cnext = softmax(B); optionally Blog = B ----
__global__ __launch_bounds__(256) void k_bsm(const float* __restrict__ dotB,
                                             float* __restrict__ Bws,
                                             float* __restrict__ Cnext,
                                             float* __restrict__ Blog) {
  int row = blockIdx.x * 256 + threadIdx.x;   // 16 blocks -> 4096 rows
  size_t o = (size_t)row * 16;
  f32x4 bv[4];
#pragma unroll
  for (int q = 0; q < 4; ++q) {
    f32x4 p = *(const f32x4*)(Bws + o + q * 4);
    f32x4 d = *(const f32x4*)(dotB + o + q * 4);
    bv[q].x = p.x + d.x; bv[q].y = p.y + d.y;
    bv[q].z = p.z + d.z; bv[q].w = p.w + d.w;
  }
  float mx = -1e30f;
#pragma unroll
  for (int q = 0; q < 4; ++q)
    mx = fmaxf(mx, fmaxf(fmaxf(bv[q].x, bv[q].y), fmaxf(bv[q].z, bv[q].w)));
  f32x4 ev[4];
  float sum = 0.f;
#pragma unroll
  for (int q = 0; q < 4; ++q) {
    ev[q].x = __expf(bv[q].x - mx); sum += ev[q].x;
    ev[q].y = __expf(bv[q].y - mx); sum += ev[q].y;
    ev[q].z = __expf(bv[q].z - mx); sum += ev[q].z;
    ev[q].w = __expf(bv[q].w - mx); sum += ev[q].w;
  }
  float r = __frcp_rn(sum);
#pragma unroll
  for (int q = 0; q < 4; ++q) {
    ev[q].x *= r; ev[q].y *= r; ev[q].z *= r; ev[q].w *= r;
    *(f32x4*)(Cnext + o + q * 4) = ev[q];
    *(f32x4*)(Bws + o + q * 4) = bv[q];
    if (Blog) *(f32x4*)(Blog + o + q * 4) = bv[q];
  }
}

extern "C" void kernel_launch(void* const* d_in, const int* in_sizes, int n_in,
                              void* d_out, int out_size, void* d_ws, size_t ws_size,
                              hipStream_t stream) {
  const float* x = (const float*)d_in[0];
  const float* W = (const float*)d_in[1];
  float* out = (float*)d_out;
  float* Vout = out;                          // 32*16*512 = 262144
  float* Cout = out + 262144;                 // 3*32*128*16 = 196608
  float* Blog = out + 262144 + 196608;        // 32*128*16 = 65536

  char* ws = (char*)d_ws;
  u16* uhat = (u16*)ws;                                   // 0 .. 64MB
  u16* xb   = (u16*)(ws + 67108864);                      // 64 .. 72MB
  u16* wt   = (u16*)(ws + 75497472);                      // 72 .. 88MB
  float* dotB = (float*)(ws + 92274688);                  // 256KB
  float* Bws  = (float*)(ws + 92536832);                  // 256KB (peak 88.5MB, proven)

  k_convx<<<4096, 256, 0, stream>>>(x, xb);
  k_transW<<<dim3(256, 32), 256, 0, stream>>>(W, wt);
  k_init<<<64, 256, 0, stream>>>(Cout, Bws);              // C1 = 1/16, B = 0
  k_gemm_tanh<<<dim3(64, 32), 256, 0, stream>>>(xb, wt, uhat);
  // iter1: S1/V1 + dot1 fused; B1 = 0 + dot1; C2 = softmax(B1)
  k_fused<0><<<dim3(16, 32), 256, 0, stream>>>(uhat, Cout, dotB);
  k_bsm<<<16, 256, 0, stream>>>(dotB, Bws, Cout + 65536, nullptr);
  // iter2: S2/V2 + dot2; B2 = B1 + dot2 (= B_logits); C3 = softmax(B2)
  k_fused<0><<<dim3(16, 32), 256, 0, stream>>>(uhat, Cout + 65536, dotB);
  k_bsm<<<16, 256, 0, stream>>>(dotB, Bws, Cout + 2 * 65536, Blog);
  // iter3: V3 = squash(sum_s C3*uhat) -> output V
  k_fused<1><<<dim3(16, 32), 256, 0, stream>>>(uhat, Cout + 2 * 65536, Vout);
}

// Round 6
// 232.283 us; speedup vs baseline: 1.2381x; 1.0216x over previous
//
#include <hip/hip_runtime.h>
#include <math.h>

typedef float f32x4 __attribute__((ext_vector_type(4)));
typedef int   i32x4 __attribute__((ext_vector_type(4)));
typedef unsigned short u16;
typedef u16 u16x4 __attribute__((ext_vector_type(4)));

#define NG 8192   // NCAPS*DCAPS
#define KG 1024

__device__ __forceinline__ u16 f2bf(float f) {
  unsigned u = __builtin_bit_cast(unsigned, f);
  u += 0x7fffu + ((u >> 16) & 1u);   // RNE
  return (u16)(u >> 16);
}
__device__ __forceinline__ float bflo(unsigned u) {
  return __builtin_bit_cast(float, u << 16);
}
__device__ __forceinline__ float bfhi(unsigned u) {
  return __builtin_bit_cast(float, u & 0xffff0000u);
}

__device__ __forceinline__ void gload16(const void* g, void* l) {
  __builtin_amdgcn_global_load_lds(
      (const __attribute__((address_space(1))) void*)g,
      (__attribute__((address_space(3))) void*)l, 16, 0, 0);
}

__device__ __forceinline__ f32x4 mfma_bf16(i32x4 a, i32x4 b, f32x4 c) {
  asm("v_mfma_f32_16x16x32_bf16 %0, %1, %2, %0" : "+v"(c) : "v"(a), "v"(b));
  return c;
}

__device__ __forceinline__ float fast_tanh(float x) {
  float ax = fabsf(x);
  float e = __expf(-2.0f * ax);
  float r = (1.0f - e) * __frcp_rn(1.0f + e);
  return copysignf(r, x);
}

// ---- x f32 (4096x1024) -> bf16 same layout ---- (round-1 proven)
__global__ __launch_bounds__(256) void k_convx(const float* __restrict__ x,
                                               u16* __restrict__ xb) {
  int i = blockIdx.x * 256 + threadIdx.x;
  f32x4 v = ((const f32x4*)x)[i];
  u16x4 r = { f2bf(v.x), f2bf(v.y), f2bf(v.z), f2bf(v.w) };
  ((u16x4*)xb)[i] = r;
}

// ---- W f32 (1024x8192) -> Wt bf16 (8192x1024) ---- (round-1 proven)
__global__ __launch_bounds__(256) void k_transW(const float* __restrict__ W,
                                                u16* __restrict__ wt) {
  __shared__ float tile[32][33];
  const int n0 = blockIdx.x * 32;
  const int k0 = blockIdx.y * 32;
  const int tx = threadIdx.x & 31;
  const int ty = threadIdx.x >> 5;
#pragma unroll
  for (int r = 0; r < 32; r += 8)
    tile[ty + r][tx] = W[(size_t)(k0 + ty + r) * NG + n0 + tx];
  __syncthreads();
#pragma unroll
  for (int r = 0; r < 32; r += 8)
    wt[(size_t)(n0 + ty + r) * KG + k0 + tx] = f2bf(tile[tx][ty + r]);
}

// ---- init C1 = 1/16 and B = 0 ---- (round-4 proven)
__global__ __launch_bounds__(256) void k_init(float* __restrict__ C0,
                                              float* __restrict__ Bws) {
  int i = blockIdx.x * 256 + threadIdx.x;   // 64 blocks * 256 = 16384 f32x4
  f32x4 c = { 0.0625f, 0.0625f, 0.0625f, 0.0625f };
  f32x4 z = {};
  ((f32x4*)C0)[i] = c;
  ((f32x4*)Bws)[i] = z;
}

// ---- GEMM + tanh: uhat = tanh(xb @ wt^T), bf16 out ---- (round-4 proven)
__global__ __launch_bounds__(256) void k_gemm_tanh(const u16* __restrict__ xb,
                                                   const u16* __restrict__ wt,
                                                   u16* __restrict__ uhat) {
  __shared__ u16 As[2][128 * 32];
  __shared__ u16 Bs[2][128 * 32];
  const int m0 = blockIdx.y * 128;
  const int n0 = blockIdx.x * 128;
  const int t = threadIdx.x;
  const int lane = t & 63;
  const int wave = t >> 6;
  const int wr = (wave >> 1) * 64;
  const int wc = (wave & 1) * 64;
  f32x4 acc[4][4] = {};

  const int r0 = t >> 2;
  const int r1 = 64 + (t >> 2);
  const int c0 = (t & 3) * 8;
  const u16* ga0 = xb + (size_t)(m0 + r0) * KG + c0;
  const u16* ga1 = xb + (size_t)(m0 + r1) * KG + c0;
  const u16* gb0 = wt + (size_t)(n0 + r0) * KG + c0;
  const u16* gb1 = wt + (size_t)(n0 + r1) * KG + c0;

  const int am = lane & 15;
  const int ak = (lane >> 4) * 8;

  for (int kt = 0; kt < KG; kt += 64) {
#pragma unroll
    for (int kh = 0; kh < 2; ++kh) {
      const int ko = kt + kh * 32;
      gload16(ga0 + ko, &As[kh][t * 8]);
      gload16(ga1 + ko, &As[kh][(256 + t) * 8]);
      gload16(gb0 + ko, &Bs[kh][t * 8]);
      gload16(gb1 + ko, &Bs[kh][(256 + t) * 8]);
    }
    __syncthreads();
#pragma unroll
    for (int kh = 0; kh < 2; ++kh) {
      i32x4 af[4], bf[4];
#pragma unroll
      for (int mi = 0; mi < 4; ++mi)
        af[mi] = *(const i32x4*)&As[kh][(wr + mi * 16 + am) * 32 + ak];
#pragma unroll
      for (int ni = 0; ni < 4; ++ni)
        bf[ni] = *(const i32x4*)&Bs[kh][(wc + ni * 16 + am) * 32 + ak];
#pragma unroll
      for (int mi = 0; mi < 4; ++mi)
#pragma unroll
        for (int ni = 0; ni < 4; ++ni)
          acc[mi][ni] = mfma_bf16(af[mi], bf[ni], acc[mi][ni]);
    }
    __syncthreads();
  }

  const int crow0 = (lane >> 4) * 4;
  const int ccol = lane & 15;
#pragma unroll
  for (int mi = 0; mi < 4; ++mi)
#pragma unroll
    for (int ni = 0; ni < 4; ++ni)
#pragma unroll
      for (int j = 0; j < 4; ++j) {
        int row = m0 + wr + mi * 16 + crow0 + j;
        int col = n0 + wc + ni * 16 + ccol;
        uhat[(size_t)row * NG + col] = f2bf(fast_tanh(acc[mi][ni][j]));
      }
}

// ---- Fused routing, d-split: block (n, b, H) owns d-half H (256 elems).
// Stage U-half in LDS (64KB, 2 blocks/CU); S_H = sum_s C[s]*U[s,dH];
// ss_H = ||S_H||^2 -> ssp[H]; MODE 0: rawdot_H[s] = U[s,dH].S_H -> rdot[H];
// MODE 1: raw S_H -> Vraw (k_vnorm normalizes).
// LDS chunk-swizzle: LDS slot j of row r holds global chunk j^(r&7)
// (pre-swizzled per-lane GLOBAL src; linear LDS dest for gload_lds).
template <int MODE>
__global__ __launch_bounds__(256) void k_fused(const u16* __restrict__ uhat,
                                               const float* __restrict__ C,
                                               float* __restrict__ rdot,
                                               float* __restrict__ ssp,
                                               float* __restrict__ Vraw) {
  __shared__ u16 Us[128 * 256];    // 64 KB
  __shared__ float Sred[8][256];   // 8 KB; Sred[0] reused as raw-S after reduce
  __shared__ float cl[128];
  __shared__ float red[4];
  const int n = blockIdx.x;   // 16
  const int b = blockIdx.y;   // 32
  const int H = blockIdx.z;   // 2
  const int t = threadIdx.x;
  const int lane = t & 63;
  const int w = t >> 6;
  const int l32 = lane & 31;
  const int hi = lane >> 5;
  const u16* Ub = uhat + ((size_t)b * 128) * NG + n * 512 + H * 256;

  if (t < 128) cl[t] = C[((size_t)b * 128 + t) * 16 + n];

  // stage: each wave-shot covers rows (r, r+1): lanes<32 row r, lanes>=32 row r+1
#pragma unroll
  for (int i = 0; i < 16; ++i) {
    const int r = w * 2 + i * 8;        // even
    const int rr = r + hi;
    gload16(Ub + (size_t)rr * NG + ((l32 ^ (rr & 7)) * 8), &Us[r * 256]);
  }
  __syncthreads();

  // S-phase: same (w,i,hi)->row map; lane accumulates d-chunk l32 (8 elems)
  float a[8] = {};
#pragma unroll
  for (int i = 0; i < 16; ++i) {
    const int s = w * 2 + i * 8 + hi;
    const float c = cl[s];
    i32x4 u = *(const i32x4*)&Us[s * 256 + ((l32 ^ (s & 7)) * 8)];
    a[0] = fmaf(c, bflo(u.x), a[0]); a[1] = fmaf(c, bfhi(u.x), a[1]);
    a[2] = fmaf(c, bflo(u.y), a[2]); a[3] = fmaf(c, bfhi(u.y), a[3]);
    a[4] = fmaf(c, bflo(u.z), a[4]); a[5] = fmaf(c, bfhi(u.z), a[5]);
    a[6] = fmaf(c, bflo(u.w), a[6]); a[7] = fmaf(c, bfhi(u.w), a[7]);
  }
  {
    const int j = w * 2 + hi;
#pragma unroll
    for (int e = 0; e < 8; ++e) Sred[j][l32 * 8 + e] = a[e];
  }
  __syncthreads();

  // reduce: thread t owns d=t (column-private read+write)
  float S = 0.f;
#pragma unroll
  for (int j2 = 0; j2 < 8; ++j2) S += Sred[j2][t];
  float ssq = S * S;
#pragma unroll
  for (int m = 1; m < 64; m <<= 1) ssq += __shfl_xor(ssq, m);
  if (lane == 0) red[w] = ssq;
  Sred[0][t] = S;                 // raw S_H for dot phase
  __syncthreads();
  const float sstot = red[0] + red[1] + red[2] + red[3];
  if (t == 0) ssp[H * 512 + b * 16 + n] = sstot;

  if (MODE == 1) {
    Vraw[((size_t)b * 16 + n) * 512 + H * 256 + t] = S;
  } else {
    // dot phase: 2 threads per s; u2 picks 128-elem quarter
    const int s = t >> 1, u2 = t & 1;
    float dot = 0.f;
#pragma unroll
    for (int i = 0; i < 16; ++i) {
      const int chunk = u2 * 16 + i;
      i32x4 uv = *(const i32x4*)&Us[s * 256 + ((chunk ^ (s & 7)) * 8)];
      f32x4 v0 = *(const f32x4*)&Sred[0][chunk * 8];
      f32x4 v1 = *(const f32x4*)&Sred[0][chunk * 8 + 4];
      dot = fmaf(bflo(uv.x), v0.x, dot);
      dot = fmaf(bfhi(uv.x), v0.y, dot);
      dot = fmaf(bflo(uv.y), v0.z, dot);
      dot = fmaf(bfhi(uv.y), v0.w, dot);
      dot = fmaf(bflo(uv.z), v1.x, dot);
      dot = fmaf(bfhi(uv.z), v1.y, dot);
      dot = fmaf(bflo(uv.w), v1.z, dot);
      dot = fmaf(bfhi(uv.w), v1.w, dot);
    }
    dot += __shfl_xor(dot, 1);
    if (u2 == 0)
      rdot[(size_t)H * 65536 + ((size_t)b * 128 + s) * 16 + n] = dot;
  }
}

// ---- dot = (rd0+rd1)*rsqrt(ss0+ss1+eps); B += dot; Cnext = softmax(B) ----
__global__ __launch_bounds__(256) void k_bsm(const float* __restrict__ rdot,
                                             const float* __restrict__ ssp,
                                             float* __restrict__ Bws,
                                             float* __restrict__ Cnext,
                                             float* __restrict__ Blog) {
  int row = blockIdx.x * 256 + threadIdx.x;   // 16 blocks -> 4096 rows
  int b = row >> 7;
  size_t o = (size_t)row * 16;
  f32x4 bv[4];
#pragma unroll
  for (int q = 0; q < 4; ++q) {
    f32x4 d0 = *(const f32x4*)(rdot + o + q * 4);
    f32x4 d1 = *(const f32x4*)(rdot + 65536 + o + q * 4);
    f32x4 s0 = *(const f32x4*)(ssp + b * 16 + q * 4);
    f32x4 s1 = *(const f32x4*)(ssp + 512 + b * 16 + q * 4);
    f32x4 p  = *(const f32x4*)(Bws + o + q * 4);
    bv[q].x = p.x + (d0.x + d1.x) * rsqrtf(s0.x + s1.x + 1e-7f);
    bv[q].y = p.y + (d0.y + d1.y) * rsqrtf(s0.y + s1.y + 1e-7f);
    bv[q].z = p.z + (d0.z + d1.z) * rsqrtf(s0.z + s1.z + 1e-7f);
    bv[q].w = p.w + (d0.w + d1.w) * rsqrtf(s0.w + s1.w + 1e-7f);
  }
  float mx = -1e30f;
#pragma unroll
  for (int q = 0; q < 4; ++q)
    mx = fmaxf(mx, fmaxf(fmaxf(bv[q].x, bv[q].y), fmaxf(bv[q].z, bv[q].w)));
  f32x4 ev[4];
  float sum = 0.f;
#pragma unroll
  for (int q = 0; q < 4; ++q) {
    ev[q].x = __expf(bv[q].x - mx); sum += ev[q].x;
    ev[q].y = __expf(bv[q].y - mx); sum += ev[q].y;
    ev[q].z = __expf(bv[q].z - mx); sum += ev[q].z;
    ev[q].w = __expf(bv[q].w - mx); sum += ev[q].w;
  }
  float r = __frcp_rn(sum);
#pragma unroll
  for (int q = 0; q < 4; ++q) {
    ev[q].x *= r; ev[q].y *= r; ev[q].z *= r; ev[q].w *= r;
    *(f32x4*)(Cnext + o + q * 4) = ev[q];
    *(f32x4*)(Bws + o + q * 4) = bv[q];
    if (Blog) *(f32x4*)(Blog + o + q * 4) = bv[q];
  }
}

// ---- V *= rsqrt(ss0+ss1+eps), in place ----
__global__ __launch_bounds__(256) void k_vnorm(float* __restrict__ V,
                                               const float* __restrict__ ssp) {
  int i = blockIdx.x * 256 + threadIdx.x;   // 128 blocks -> 32768 x 8 elems
  int bn = i >> 6;                          // (i*8)>>9
  float rs = rsqrtf(ssp[bn] + ssp[512 + bn] + 1e-7f);
  f32x4 v0 = *(const f32x4*)(V + (size_t)i * 8);
  f32x4 v1 = *(const f32x4*)(V + (size_t)i * 8 + 4);
  v0.x *= rs; v0.y *= rs; v0.z *= rs; v0.w *= rs;
  v1.x *= rs; v1.y *= rs; v1.z *= rs; v1.w *= rs;
  *(f32x4*)(V + (size_t)i * 8) = v0;
  *(f32x4*)(V + (size_t)i * 8 + 4) = v1;
}

extern "C" void kernel_launch(void* const* d_in, const int* in_sizes, int n_in,
                              void* d_out, int out_size, void* d_ws, size_t ws_size,
                              hipStream_t stream) {
  const float* x = (const float*)d_in[0];
  const float* W = (const float*)d_in[1];
  float* out = (float*)d_out;
  float* Vout = out;                          // 32*16*512 = 262144
  float* Cout = out + 262144;                 // 3*32*128*16 = 196608
  float* Blog = out + 262144 + 196608;        // 32*128*16 = 65536

  char* ws = (char*)d_ws;
  u16* uhat  = (u16*)ws;                      // 0 .. 64MB
  u16* xb    = (u16*)(ws + 67108864);         // 64 .. 72MB
  u16* wt    = (u16*)(ws + 75497472);         // 72 .. 88MB
  float* rdot = (float*)(ws + 92274688);      // 512KB ([2][4096][16])
  float* ssp  = (float*)(ws + 92798976);      // 4KB ([2][512])
  float* Bws  = (float*)(ws + 92803072);      // 256KB (peak ~88.8MB, proven ws)

  k_convx<<<4096, 256, 0, stream>>>(x, xb);
  k_transW<<<dim3(256, 32), 256, 0, stream>>>(W, wt);
  k_init<<<64, 256, 0, stream>>>(Cout, Bws);              // C1 = 1/16, B = 0
  k_gemm_tanh<<<dim3(64, 32), 256, 0, stream>>>(xb, wt, uhat);
  // iter1: raw dots + ss partials; B1 = 0 + dot1; C2 = softmax(B1)
  k_fused<0><<<dim3(16, 32, 2), 256, 0, stream>>>(uhat, Cout, rdot, ssp, nullptr);
  k_bsm<<<16, 256, 0, stream>>>(rdot, ssp, Bws, Cout + 65536, nullptr);
  // iter2: B2 = B1 + dot2 (= B_logits); C3 = softmax(B2)
  k_fused<0><<<dim3(16, 32, 2), 256, 0, stream>>>(uhat, Cout + 65536, rdot, ssp, nullptr);
  k_bsm<<<16, 256, 0, stream>>>(rdot, ssp, Bws, Cout + 2 * 65536, Blog);
  // iter3: raw V3 halves + ss; k_vnorm applies squash scale
  k_fused<1><<<dim3(16, 32, 2), 256, 0, stream>>>(uhat, Cout + 2 * 65536, nullptr, ssp, Vout);
  k_vnorm<<<128, 256, 0, stream>>>(Vout, ssp);
}

// Round 8
// 231.962 us; speedup vs baseline: 1.2398x; 1.0014x over previous
//
#include <hip/hip_runtime.h>
#include <math.h>

typedef float f32x4 __attribute__((ext_vector_type(4)));
typedef int   i32x4 __attribute__((ext_vector_type(4)));
typedef unsigned short u16;
typedef u16 u16x4 __attribute__((ext_vector_type(4)));

#define NG 8192   // NCAPS*DCAPS
#define KG 1024

__device__ __forceinline__ u16 f2bf(float f) {
  unsigned u = __builtin_bit_cast(unsigned, f);
  u += 0x7fffu + ((u >> 16) & 1u);   // RNE
  return (u16)(u >> 16);
}
__device__ __forceinline__ float bflo(unsigned u) {
  return __builtin_bit_cast(float, u << 16);
}
__device__ __forceinline__ float bfhi(unsigned u) {
  return __builtin_bit_cast(float, u & 0xffff0000u);
}

__device__ __forceinline__ void gload16(const void* g, void* l) {
  __builtin_amdgcn_global_load_lds(
      (const __attribute__((address_space(1))) void*)g,
      (__attribute__((address_space(3))) void*)l, 16, 0, 0);
}

__device__ __forceinline__ f32x4 mfma_bf16(i32x4 a, i32x4 b, f32x4 c) {
  asm("v_mfma_f32_16x16x32_bf16 %0, %1, %2, %0" : "+v"(c) : "v"(a), "v"(b));
  return c;
}

__device__ __forceinline__ float fast_tanh(float x) {
  float ax = fabsf(x);
  float e = __expf(-2.0f * ax);
  float r = (1.0f - e) * __frcp_rn(1.0f + e);
  return copysignf(r, x);
}

// ---- x f32 (4096x1024) -> bf16 same layout ---- (round-1 proven)
__global__ __launch_bounds__(256) void k_convx(const float* __restrict__ x,
                                               u16* __restrict__ xb) {
  int i = blockIdx.x * 256 + threadIdx.x;
  f32x4 v = ((const f32x4*)x)[i];
  u16x4 r = { f2bf(v.x), f2bf(v.y), f2bf(v.z), f2bf(v.w) };
  ((u16x4*)xb)[i] = r;
}

// ---- W f32 (1024x8192) -> Wt bf16 (8192x1024) ---- (round-1 proven)
__global__ __launch_bounds__(256) void k_transW(const float* __restrict__ W,
                                                u16* __restrict__ wt) {
  __shared__ float tile[32][33];
  const int n0 = blockIdx.x * 32;
  const int k0 = blockIdx.y * 32;
  const int tx = threadIdx.x & 31;
  const int ty = threadIdx.x >> 5;
#pragma unroll
  for (int r = 0; r < 32; r += 8)
    tile[ty + r][tx] = W[(size_t)(k0 + ty + r) * NG + n0 + tx];
  __syncthreads();
#pragma unroll
  for (int r = 0; r < 32; r += 8)
    wt[(size_t)(n0 + ty + r) * KG + k0 + tx] = f2bf(tile[tx][ty + r]);
}

// ---- init C1 = 1/16 and B = 0 ---- (round-4 proven)
__global__ __launch_bounds__(256) void k_init(float* __restrict__ C0,
                                              float* __restrict__ Bws) {
  int i = blockIdx.x * 256 + threadIdx.x;   // 64 blocks * 256 = 16384 f32x4
  f32x4 c = { 0.0625f, 0.0625f, 0.0625f, 0.0625f };
  f32x4 z = {};
  ((f32x4*)C0)[i] = c;
  ((f32x4*)Bws)[i] = z;
}

// ---- GEMM + tanh: uhat = tanh(xb @ wt^T), bf16 out ---- (round-4 proven)
__global__ __launch_bounds__(256) void k_gemm_tanh(const u16* __restrict__ xb,
                                                   const u16* __restrict__ wt,
                                                   u16* __restrict__ uhat) {
  __shared__ u16 As[2][128 * 32];
  __shared__ u16 Bs[2][128 * 32];
  const int m0 = blockIdx.y * 128;
  const int n0 = blockIdx.x * 128;
  const int t = threadIdx.x;
  const int lane = t & 63;
  const int wave = t >> 6;
  const int wr = (wave >> 1) * 64;
  const int wc = (wave & 1) * 64;
  f32x4 acc[4][4] = {};

  const int r0 = t >> 2;
  const int r1 = 64 + (t >> 2);
  const int c0 = (t & 3) * 8;
  const u16* ga0 = xb + (size_t)(m0 + r0) * KG + c0;
  const u16* ga1 = xb + (size_t)(m0 + r1) * KG + c0;
  const u16* gb0 = wt + (size_t)(n0 + r0) * KG + c0;
  const u16* gb1 = wt + (size_t)(n0 + r1) * KG + c0;

  const int am = lane & 15;
  const int ak = (lane >> 4) * 8;

  for (int kt = 0; kt < KG; kt += 64) {
#pragma unroll
    for (int kh = 0; kh < 2; ++kh) {
      const int ko = kt + kh * 32;
      gload16(ga0 + ko, &As[kh][t * 8]);
      gload16(ga1 + ko, &As[kh][(256 + t) * 8]);
      gload16(gb0 + ko, &Bs[kh][t * 8]);
      gload16(gb1 + ko, &Bs[kh][(256 + t) * 8]);
    }
    __syncthreads();
#pragma unroll
    for (int kh = 0; kh < 2; ++kh) {
      i32x4 af[4], bf[4];
#pragma unroll
      for (int mi = 0; mi < 4; ++mi)
        af[mi] = *(const i32x4*)&As[kh][(wr + mi * 16 + am) * 32 + ak];
#pragma unroll
      for (int ni = 0; ni < 4; ++ni)
        bf[ni] = *(const i32x4*)&Bs[kh][(wc + ni * 16 + am) * 32 + ak];
#pragma unroll
      for (int mi = 0; mi < 4; ++mi)
#pragma unroll
        for (int ni = 0; ni < 4; ++ni)
          acc[mi][ni] = mfma_bf16(af[mi], bf[ni], acc[mi][ni]);
    }
    __syncthreads();
  }

  const int crow0 = (lane >> 4) * 4;
  const int ccol = lane & 15;
#pragma unroll
  for (int mi = 0; mi < 4; ++mi)
#pragma unroll
    for (int ni = 0; ni < 4; ++ni)
#pragma unroll
      for (int j = 0; j < 4; ++j) {
        int row = m0 + wr + mi * 16 + crow0 + j;
        int col = n0 + wc + ni * 16 + ccol;
        uhat[(size_t)row * NG + col] = f2bf(fast_tanh(acc[mi][ni][j]));
      }
}

// ---- Fused routing, d-split + PIPELINED staging (counted vmcnt).
// Block (n, b, H) owns d-half H. Stage map == S-phase consume map (wave-
// private rows), so chunk i is consumable after s_waitcnt vmcnt(15-i) with
// NO barrier. Dot phase (needs all rows) runs after one __syncthreads.
// LDS chunk-swizzle: LDS slot j of row r holds global chunk j^(r&7).
template <int MODE>
__global__ __launch_bounds__(256) void k_fused(const u16* __restrict__ uhat,
                                               const float* __restrict__ C,
                                               float* __restrict__ rdot,
                                               float* __restrict__ ssp,
                                               float* __restrict__ Vraw) {
  __shared__ u16 Us[128 * 256];    // 64 KB
  __shared__ float Sred[8][256];   // 8 KB; Sred[0] reused as raw-S after reduce
  __shared__ float cl[128];
  __shared__ float red[4];
  const int n = blockIdx.x;   // 16
  const int b = blockIdx.y;   // 32
  const int H = blockIdx.z;   // 2
  const int t = threadIdx.x;
  const int lane = t & 63;
  const int w = t >> 6;
  const int l32 = lane & 31;
  const int hi = lane >> 5;
  const u16* Ub = uhat + ((size_t)b * 128) * NG + n * 512 + H * 256;

  if (t < 128) cl[t] = C[((size_t)b * 128 + t) * 16 + n];
  __syncthreads();   // cl visible to all waves; vmcnt drained (clean count)

  // issue ALL 16 stage loads back-to-back (wave-private rows)
#pragma unroll
  for (int i = 0; i < 16; ++i) {
    const int r = w * 2 + i * 8;        // even
    const int rr = r + hi;
    gload16(Ub + (size_t)rr * NG + ((l32 ^ (rr & 7)) * 8), &Us[r * 256]);
  }

  // consume chunk i once its load (the i-th issued) has retired
  float a[8] = {};
#define SSTEP(cnt, i)                                                        \
  do {                                                                       \
    asm volatile("s_waitcnt vmcnt(" #cnt ")" ::: "memory");                  \
    const int s = w * 2 + (i) * 8 + hi;                                      \
    const float c = cl[s];                                                   \
    i32x4 u = *(const i32x4*)&Us[s * 256 + ((l32 ^ (s & 7)) * 8)];           \
    a[0] = fmaf(c, bflo(u.x), a[0]); a[1] = fmaf(c, bfhi(u.x), a[1]);        \
    a[2] = fmaf(c, bflo(u.y), a[2]); a[3] = fmaf(c, bfhi(u.y), a[3]);        \
    a[4] = fmaf(c, bflo(u.z), a[4]); a[5] = fmaf(c, bfhi(u.z), a[5]);        \
    a[6] = fmaf(c, bflo(u.w), a[6]); a[7] = fmaf(c, bfhi(u.w), a[7]);        \
  } while (0)
  SSTEP(15, 0);  SSTEP(14, 1);  SSTEP(13, 2);  SSTEP(12, 3);
  SSTEP(11, 4);  SSTEP(10, 5);  SSTEP(9, 6);   SSTEP(8, 7);
  SSTEP(7, 8);   SSTEP(6, 9);   SSTEP(5, 10);  SSTEP(4, 11);
  SSTEP(3, 12);  SSTEP(2, 13);  SSTEP(1, 14);  SSTEP(0, 15);
#undef SSTEP

  {
    const int j = w * 2 + hi;
#pragma unroll
    for (int e = 0; e < 8; ++e) Sred[j][l32 * 8 + e] = a[e];
  }
  __syncthreads();   // all rows staged (vmcnt==0 already) + Sred visible

  // reduce: thread t owns d=t (column-private read+write)
  float S = 0.f;
#pragma unroll
  for (int j2 = 0; j2 < 8; ++j2) S += Sred[j2][t];
  float ssq = S * S;
#pragma unroll
  for (int m = 1; m < 64; m <<= 1) ssq += __shfl_xor(ssq, m);
  if (lane == 0) red[w] = ssq;
  Sred[0][t] = S;                 // raw S_H for dot phase
  __syncthreads();
  const float sstot = red[0] + red[1] + red[2] + red[3];
  if (t == 0) ssp[H * 512 + b * 16 + n] = sstot;

  if (MODE == 1) {
    Vraw[((size_t)b * 16 + n) * 512 + H * 256 + t] = S;
  } else {
    // dot phase: 2 threads per s; u2 picks 128-elem quarter
    const int s = t >> 1, u2 = t & 1;
    float dot = 0.f;
#pragma unroll
    for (int i = 0; i < 16; ++i) {
      const int chunk = u2 * 16 + i;
      i32x4 uv = *(const i32x4*)&Us[s * 256 + ((chunk ^ (s & 7)) * 8)];
      f32x4 v0 = *(const f32x4*)&Sred[0][chunk * 8];
      f32x4 v1 = *(const f32x4*)&Sred[0][chunk * 8 + 4];
      dot = fmaf(bflo(uv.x), v0.x, dot);
      dot = fmaf(bfhi(uv.x), v0.y, dot);
      dot = fmaf(bflo(uv.y), v0.z, dot);
      dot = fmaf(bfhi(uv.y), v0.w, dot);
      dot = fmaf(bflo(uv.z), v1.x, dot);
      dot = fmaf(bfhi(uv.z), v1.y, dot);
      dot = fmaf(bflo(uv.w), v1.z, dot);
      dot = fmaf(bfhi(uv.w), v1.w, dot);
    }
    dot += __shfl_xor(dot, 1);
    if (u2 == 0)
      rdot[(size_t)H * 65536 + ((size_t)b * 128 + s) * 16 + n] = dot;
  }
}

// ---- dot = (rd0+rd1)*rsqrt(ss0+ss1+eps); B += dot; Cnext = softmax(B) ----
__global__ __launch_bounds__(256) void k_bsm(const float* __restrict__ rdot,
                                             const float* __restrict__ ssp,
                                             float* __restrict__ Bws,
                                             float* __restrict__ Cnext,
                                             float* __restrict__ Blog) {
  int row = blockIdx.x * 256 + threadIdx.x;   // 16 blocks -> 4096 rows
  int b = row >> 7;
  size_t o = (size_t)row * 16;
  f32x4 bv[4];
#pragma unroll
  for (int q = 0; q < 4; ++q) {
    f32x4 d0 = *(const f32x4*)(rdot + o + q * 4);
    f32x4 d1 = *(const f32x4*)(rdot + 65536 + o + q * 4);
    f32x4 s0 = *(const f32x4*)(ssp + b * 16 + q * 4);
    f32x4 s1 = *(const f32x4*)(ssp + 512 + b * 16 + q * 4);
    f32x4 p  = *(const f32x4*)(Bws + o + q * 4);
    bv[q].x = p.x + (d0.x + d1.x) * rsqrtf(s0.x + s1.x + 1e-7f);
    bv[q].y = p.y + (d0.y + d1.y) * rsqrtf(s0.y + s1.y + 1e-7f);
    bv[q].z = p.z + (d0.z + d1.z) * rsqrtf(s0.z + s1.z + 1e-7f);
    bv[q].w = p.w + (d0.w + d1.w) * rsqrtf(s0.w + s1.w + 1e-7f);
  }
  float mx = -1e30f;
#pragma unroll
  for (int q = 0; q < 4; ++q)
    mx = fmaxf(mx, fmaxf(fmaxf(bv[q].x, bv[q].y), fmaxf(bv[q].z, bv[q].w)));
  f32x4 ev[4];
  float sum = 0.f;
#pragma unroll
  for (int q = 0; q < 4; ++q) {
    ev[q].x = __expf(bv[q].x - mx); sum += ev[q].x;
    ev[q].y = __expf(bv[q].y - mx); sum += ev[q].y;
    ev[q].z = __expf(bv[q].z - mx); sum += ev[q].z;
    ev[q].w = __expf(bv[q].w - mx); sum += ev[q].w;
  }
  float r = __frcp_rn(sum);
#pragma unroll
  for (int q = 0; q < 4; ++q) {
    ev[q].x *= r; ev[q].y *= r; ev[q].z *= r; ev[q].w *= r;
    *(f32x4*)(Cnext + o + q * 4) = ev[q];
    *(f32x4*)(Bws + o + q * 4) = bv[q];
    if (Blog) *(f32x4*)(Blog + o + q * 4) = bv[q];
  }
}

// ---- V *= rsqrt(ss0+ss1+eps), in place ----
__global__ __launch_bounds__(256) void k_vnorm(float* __restrict__ V,
                                               const float* __restrict__ ssp) {
  int i = blockIdx.x * 256 + threadIdx.x;   // 128 blocks -> 32768 x 8 elems
  int bn = i >> 6;                          // (i*8)>>9
  float rs = rsqrtf(ssp[bn] + ssp[512 + bn] + 1e-7f);
  f32x4 v0 = *(const f32x4*)(V + (size_t)i * 8);
  f32x4 v1 = *(const f32x4*)(V + (size_t)i * 8 + 4);
  v0.x *= rs; v0.y *= rs; v0.z *= rs; v0.w *= rs;
  v1.x *= rs; v1.y *= rs; v1.z *= rs; v1.w *= rs;
  *(f32x4*)(V + (size_t)i * 8) = v0;
  *(f32x4*)(V + (size_t)i * 8 + 4) = v1;
}

extern "C" void kernel_launch(void* const* d_in, const int* in_sizes, int n_in,
                              void* d_out, int out_size, void* d_ws, size_t ws_size,
                              hipStream_t stream) {
  const float* x = (const float*)d_in[0];
  const float* W = (const float*)d_in[1];
  float* out = (float*)d_out;
  float* Vout = out;                          // 32*16*512 = 262144
  float* Cout = out + 262144;                 // 3*32*128*16 = 196608
  float* Blog = out + 262144 + 196608;        // 32*128*16 = 65536

  char* ws = (char*)d_ws;
  u16* uhat  = (u16*)ws;                      // 0 .. 64MB
  u16* xb    = (u16*)(ws + 67108864);         // 64 .. 72MB
  u16* wt    = (u16*)(ws + 75497472);         // 72 .. 88MB
  float* rdot = (float*)(ws + 92274688);      // 512KB ([2][4096][16])
  float* ssp  = (float*)(ws + 92798976);      // 4KB ([2][512])
  float* Bws  = (float*)(ws + 92803072);      // 256KB (peak ~88.8MB, proven ws)

  k_convx<<<4096, 256, 0, stream>>>(x, xb);
  k_transW<<<dim3(256, 32), 256, 0, stream>>>(W, wt);
  k_init<<<64, 256, 0, stream>>>(Cout, Bws);              // C1 = 1/16, B = 0
  k_gemm_tanh<<<dim3(64, 32), 256, 0, stream>>>(xb, wt, uhat);
  // iter1: raw dots + ss partials; B1 = 0 + dot1; C2 = softmax(B1)
  k_fused<0><<<dim3(16, 32, 2), 256, 0, stream>>>(uhat, Cout, rdot, ssp, nullptr);
  k_bsm<<<16, 256, 0, stream>>>(rdot, ssp, Bws, Cout + 65536, nullptr);
  // iter2: B2 = B1 + dot2 (= B_logits); C3 = softmax(B2)
  k_fused<0><<<dim3(16, 32, 2), 256, 0, stream>>>(uhat, Cout + 65536, rdot, ssp, nullptr);
  k_bsm<<<16, 256, 0, stream>>>(rdot, ssp, Bws, Cout + 2 * 65536, Blog);
  // iter3: raw V3 halves + ss; k_vnorm applies squash scale
  k_fused<1><<<dim3(16, 32, 2), 256, 0, stream>>>(uhat, Cout + 2 * 65536, nullptr, ssp, Vout);
  k_vnorm<<<128, 256, 0, stream>>>(Vout, ssp);
}